// Round 1
// baseline (53.503 us; speedup 1.0000x reference)
//
#include <hip/hip_runtime.h>

#define BLOCK 256
#define GRID 2048

// Per-row loss:
//   t = true[b] in {0,1,2,3}
//   dis rows: t=0:[0,1,2,3]  t=1:[1,0,2,2]  t=2:[2,2,0,1]  t=3:[3,2,1,0]
//   loss[b] = sum_c dis[t][c] * softmax(pred[b])[c]
//   out = mean_b loss[b]
// d0 = t, d3 = 3-t always; d1,d2 via packed byte tables.

__global__ __launch_bounds__(BLOCK) void sanchit_loss_kernel(
    const float4* __restrict__ pred, const int* __restrict__ tru,
    float* __restrict__ out, int B, float inv_B)
{
    const unsigned d1_tbl = 0x02020001u; // t=0->1, t=1->0, t=2->2, t=3->2
    const unsigned d2_tbl = 0x01000202u; // t=0->2, t=1->2, t=2->0, t=3->1

    float acc = 0.0f;
    const int stride = gridDim.x * blockDim.x;
    for (int i = blockIdx.x * blockDim.x + threadIdx.x; i < B; i += stride) {
        float4 pv = pred[i];     // 16B coalesced: whole softmax row per lane
        int t = tru[i];

        float m  = fmaxf(fmaxf(pv.x, pv.y), fmaxf(pv.z, pv.w));
        float e0 = __expf(pv.x - m);
        float e1 = __expf(pv.y - m);
        float e2 = __expf(pv.z - m);
        float e3 = __expf(pv.w - m);

        float d0 = (float)t;
        float d3 = (float)(3 - t);
        float d1 = (float)((d1_tbl >> (8 * t)) & 0xffu);
        float d2 = (float)((d2_tbl >> (8 * t)) & 0xffu);

        float num = d0 * e0 + d1 * e1 + d2 * e2 + d3 * e3;
        float den = e0 + e1 + e2 + e3;
        acc += __fdividef(num, den);
    }

    // wave64 butterfly-free down-shuffle reduction
    #pragma unroll
    for (int off = 32; off > 0; off >>= 1)
        acc += __shfl_down(acc, off, 64);

    __shared__ float wave_sums[BLOCK / 64];
    const int lane = threadIdx.x & 63;
    const int wid  = threadIdx.x >> 6;
    if (lane == 0) wave_sums[wid] = acc;
    __syncthreads();

    if (threadIdx.x == 0) {
        float s = 0.0f;
        #pragma unroll
        for (int w = 0; w < BLOCK / 64; ++w) s += wave_sums[w];
        atomicAdd(out, s * inv_B);  // device-scope by default on CDNA
    }
}

extern "C" void kernel_launch(void* const* d_in, const int* in_sizes, int n_in,
                              void* d_out, int out_size, void* d_ws, size_t ws_size,
                              hipStream_t stream) {
    const float4* pred = (const float4*)d_in[0];   // [B,4] f32 -> one float4/row
    const int*    tru  = (const int*)d_in[1];      // int64 in ref -> int32 on device
    float*        out  = (float*)d_out;

    const int B = in_sizes[0] / 4;                 // 8388608
    const float inv_B = 1.0f / (float)B;           // B = 2^23, exact

    hipMemsetAsync(out, 0, sizeof(float), stream); // d_out poisoned to 0xAA by harness
    sanchit_loss_kernel<<<GRID, BLOCK, 0, stream>>>(pred, tru, out, B, inv_B);
}

// Round 2
// 33.978 us; speedup vs baseline: 1.5746x; 1.5746x over previous
//
#include <hip/hip_runtime.h>

#define BLOCK 256
#define GRID 2048   // = 8 blocks/CU on 256 CUs; grid-stride covers B=2^23 rows in 16 iters/thread

// Per-row loss:
//   t = true[b] in {0,1,2,3}
//   dis rows: t=0:[0,1,2,3]  t=1:[1,0,2,2]  t=2:[2,2,0,1]  t=3:[3,2,1,0]
//   loss[b] = sum_c dis[t][c] * softmax(pred[b])[c]
//   out = mean_b loss[b]
// d0 = t, d3 = 3-t always; d1,d2 via packed byte tables.

__global__ __launch_bounds__(BLOCK) void sanchit_loss_partial(
    const float4* __restrict__ pred, const int* __restrict__ tru,
    float* __restrict__ partial, int B)
{
    const unsigned d1_tbl = 0x02020001u; // t=0->1, t=1->0, t=2->2, t=3->2
    const unsigned d2_tbl = 0x01000202u; // t=0->2, t=1->2, t=2->0, t=3->1

    float acc = 0.0f;
    const int stride = gridDim.x * blockDim.x;
    for (int i = blockIdx.x * blockDim.x + threadIdx.x; i < B; i += stride) {
        float4 pv = pred[i];     // 16B coalesced: whole softmax row per lane
        int t = tru[i];

        float m  = fmaxf(fmaxf(pv.x, pv.y), fmaxf(pv.z, pv.w));
        float e0 = __expf(pv.x - m);
        float e1 = __expf(pv.y - m);
        float e2 = __expf(pv.z - m);
        float e3 = __expf(pv.w - m);

        float d0 = (float)t;
        float d3 = (float)(3 - t);
        float d1 = (float)((d1_tbl >> (8 * t)) & 0xffu);
        float d2 = (float)((d2_tbl >> (8 * t)) & 0xffu);

        float num = d0 * e0 + d1 * e1 + d2 * e2 + d3 * e3;
        float den = e0 + e1 + e2 + e3;
        acc += __fdividef(num, den);
    }

    // wave64 down-shuffle reduction
    #pragma unroll
    for (int off = 32; off > 0; off >>= 1)
        acc += __shfl_down(acc, off, 64);

    __shared__ float wave_sums[BLOCK / 64];
    const int lane = threadIdx.x & 63;
    const int wid  = threadIdx.x >> 6;
    if (lane == 0) wave_sums[wid] = acc;
    __syncthreads();

    if (threadIdx.x == 0) {
        float s = 0.0f;
        #pragma unroll
        for (int w = 0; w < BLOCK / 64; ++w) s += wave_sums[w];
        partial[blockIdx.x] = s;   // plain store — no atomics, no same-address storm
    }
}

// One block reduces the GRID partials and writes the mean. Fixed order ->
// bit-deterministic across calls.
__global__ __launch_bounds__(BLOCK) void sanchit_loss_final(
    const float* __restrict__ partial, float* __restrict__ out, float inv_B)
{
    float acc = 0.0f;
    #pragma unroll
    for (int k = 0; k < GRID / BLOCK; ++k)
        acc += partial[threadIdx.x + k * BLOCK];

    #pragma unroll
    for (int off = 32; off > 0; off >>= 1)
        acc += __shfl_down(acc, off, 64);

    __shared__ float wave_sums[BLOCK / 64];
    const int lane = threadIdx.x & 63;
    const int wid  = threadIdx.x >> 6;
    if (lane == 0) wave_sums[wid] = acc;
    __syncthreads();

    if (threadIdx.x == 0) {
        float s = 0.0f;
        #pragma unroll
        for (int w = 0; w < BLOCK / 64; ++w) s += wave_sums[w];
        out[0] = s * inv_B;
    }
}

extern "C" void kernel_launch(void* const* d_in, const int* in_sizes, int n_in,
                              void* d_out, int out_size, void* d_ws, size_t ws_size,
                              hipStream_t stream) {
    const float4* pred = (const float4*)d_in[0];   // [B,4] f32 -> one float4/row
    const int*    tru  = (const int*)d_in[1];      // int32 on device (verified: absmax 0)
    float*        out  = (float*)d_out;
    float*        partial = (float*)d_ws;          // GRID floats = 8 KB scratch

    const int B = in_sizes[0] / 4;                 // 8388608
    const float inv_B = 1.0f / (float)B;           // B = 2^23, exact

    sanchit_loss_partial<<<GRID, BLOCK, 0, stream>>>(pred, tru, partial, B);
    sanchit_loss_final<<<1, BLOCK, 0, stream>>>(partial, out, inv_B);
}

// Round 3
// 32.089 us; speedup vs baseline: 1.6673x; 1.0589x over previous
//
#include <hip/hip_runtime.h>

#define BLOCK 256
#define GRID 2048     // 8 blocks/CU; 524288 threads
#define UNROLL 4      // 4 consecutive rows/thread -> int4 label load, 64B contiguous pred/lane

// Per-row loss:
//   t = true[b] in {0,1,2,3}
//   dis rows: t=0:[0,1,2,3]  t=1:[1,0,2,2]  t=2:[2,2,0,1]  t=3:[3,2,1,0]
//   loss[b] = sum_c dis[t][c] * softmax(pred[b])[c] ; out = mean_b loss[b]
// d0 = t, d3 = 3-t always; d1,d2 via packed byte tables.

__device__ __forceinline__ float row_loss(float4 pv, int t) {
    const unsigned d1_tbl = 0x02020001u; // t=0->1, t=1->0, t=2->2, t=3->2
    const unsigned d2_tbl = 0x01000202u; // t=0->2, t=1->2, t=2->0, t=3->1
    float m  = fmaxf(fmaxf(pv.x, pv.y), fmaxf(pv.z, pv.w));
    float e0 = __expf(pv.x - m);
    float e1 = __expf(pv.y - m);
    float e2 = __expf(pv.z - m);
    float e3 = __expf(pv.w - m);
    float d0 = (float)t;
    float d3 = (float)(3 - t);
    float d1 = (float)((d1_tbl >> (8 * t)) & 0xffu);
    float d2 = (float)((d2_tbl >> (8 * t)) & 0xffu);
    float num = d0 * e0 + d1 * e1 + d2 * e2 + d3 * e3;
    float den = e0 + e1 + e2 + e3;
    return __fdividef(num, den);
}

__global__ __launch_bounds__(BLOCK) void sanchit_loss_partial(
    const float4* __restrict__ pred, const int* __restrict__ tru,
    float* __restrict__ partial, int B)
{
    const int tid      = blockIdx.x * BLOCK + threadIdx.x;
    const int nthreads = GRID * BLOCK;

    float acc = 0.0f;
    // main loop: 4 consecutive rows per thread per iteration.
    // B=2^23, nthreads*UNROLL=2^21 -> exactly 4 iterations, no tail.
    int base = tid * UNROLL;
    for (; base + UNROLL <= B; base += nthreads * UNROLL) {
        // issue all 5 loads up front (5 VMEM in flight/thread)
        int4   t4 = ((const int4*)tru)[base / 4];
        float4 p0 = pred[base + 0];
        float4 p1 = pred[base + 1];
        float4 p2 = pred[base + 2];
        float4 p3 = pred[base + 3];
        acc += row_loss(p0, t4.x);
        acc += row_loss(p1, t4.y);
        acc += row_loss(p2, t4.z);
        acc += row_loss(p3, t4.w);
    }
    // generic tail (never runs for B=2^23, kept for safety)
    for (int i = base; i < B; ++i) {
        if ((i - tid * UNROLL) % (nthreads * UNROLL) < UNROLL)
            acc += row_loss(pred[i], tru[i]);
    }

    // wave64 down-shuffle reduction
    #pragma unroll
    for (int off = 32; off > 0; off >>= 1)
        acc += __shfl_down(acc, off, 64);

    __shared__ float wave_sums[BLOCK / 64];
    const int lane = threadIdx.x & 63;
    const int wid  = threadIdx.x >> 6;
    if (lane == 0) wave_sums[wid] = acc;
    __syncthreads();

    if (threadIdx.x == 0) {
        float s = 0.0f;
        #pragma unroll
        for (int w = 0; w < BLOCK / 64; ++w) s += wave_sums[w];
        partial[blockIdx.x] = s;   // plain store — no atomics
    }
}

// One block reduces the GRID partials and writes the mean. Fixed order ->
// bit-deterministic across calls.
__global__ __launch_bounds__(BLOCK) void sanchit_loss_final(
    const float* __restrict__ partial, float* __restrict__ out, float inv_B)
{
    float acc = 0.0f;
    #pragma unroll
    for (int k = 0; k < GRID / BLOCK; ++k)
        acc += partial[threadIdx.x + k * BLOCK];

    #pragma unroll
    for (int off = 32; off > 0; off >>= 1)
        acc += __shfl_down(acc, off, 64);

    __shared__ float wave_sums[BLOCK / 64];
    const int lane = threadIdx.x & 63;
    const int wid  = threadIdx.x >> 6;
    if (lane == 0) wave_sums[wid] = acc;
    __syncthreads();

    if (threadIdx.x == 0) {
        float s = 0.0f;
        #pragma unroll
        for (int w = 0; w < BLOCK / 64; ++w) s += wave_sums[w];
        out[0] = s * inv_B;
    }
}

extern "C" void kernel_launch(void* const* d_in, const int* in_sizes, int n_in,
                              void* d_out, int out_size, void* d_ws, size_t ws_size,
                              hipStream_t stream) {
    const float4* pred = (const float4*)d_in[0];   // [B,4] f32 -> one float4/row
    const int*    tru  = (const int*)d_in[1];      // int32 on device (verified: absmax 0)
    float*        out  = (float*)d_out;
    float*        partial = (float*)d_ws;          // GRID floats = 8 KB scratch

    const int B = in_sizes[0] / 4;                 // 8388608
    const float inv_B = 1.0f / (float)B;           // B = 2^23, exact

    sanchit_loss_partial<<<GRID, BLOCK, 0, stream>>>(pred, tru, partial, B);
    sanchit_loss_final<<<1, BLOCK, 0, stream>>>(partial, out, inv_B);
}